// Round 8
// baseline (321.524 us; speedup 1.0000x reference)
//
#include <hip/hip_runtime.h>
#include <math.h>

// Problem constants (from setup_inputs)
#define NN 100000            // nodes
#define NE 1600000           // real edges
#define ET (NE + NN)         // edges + self loops = 1,700,000
#define FIN 128
#define H1 4
#define C1 8
#define F1 32                // H1*C1
#define FOUT 16
#define NSLOPE 0.2f

// Radix-partition parameters (CSR build)
#define PARTW 256                          // nodes per dst-partition
#define PSHIFT 8
#define NPART ((NN + PARTW - 1) / PARTW)   // 391
#define CHUNK 8192                         // edges per hist/part block
#define NBLK ((ET + CHUNK - 1) / CHUNK)    // 208
#define CPAD 16                            // ints: 1 global counter per 64B line
#define SMASK 0x1FFFF                      // low 17 bits = src id

typedef _Float16 half8 __attribute__((ext_vector_type(8)));
typedef _Float16 half4_t __attribute__((ext_vector_type(4)));

// ---------------- scan helpers ----------------

__device__ inline int wave_incl_scan(int v) {
#pragma unroll
    for (int off = 1; off < 64; off <<= 1) {
        int u = __shfl_up(v, off);
        if ((threadIdx.x & 63) >= off) v += u;
    }
    return v;
}

__device__ inline int block_excl_scan(int v, int* wsum, int nw) {
    int t = threadIdx.x, wid = t >> 6, lane = t & 63;
    int incl = wave_incl_scan(v);
    if (lane == 63) wsum[wid] = incl;
    __syncthreads();
    if (wid == 0) {
        int wv = (lane < nw) ? wsum[lane] : 0;
        wv = wave_incl_scan(wv);
        if (lane < nw) wsum[lane] = wv;
    }
    __syncthreads();
    return incl - v + (wid ? wsum[wid - 1] : 0);
}

// ---------------- CSR build ----------------

// Pass 1: LDS histogram -> one global atomicAdd per (block,partition).
__global__ __launch_bounds__(1024) void k_hist(const int* __restrict__ dstA, int* __restrict__ ptotal) {
    __shared__ int h[NPART];
    int t = threadIdx.x;
    for (int i = t; i < NPART; i += 1024) h[i] = 0;
    __syncthreads();
    int base = blockIdx.x * CHUNK;
#pragma unroll
    for (int k = 0; k < CHUNK / 1024; k++) {
        int e = base + k * 1024 + t;
        if (e < ET) {
            int d = (e < NE) ? dstA[e] : (e - NE);   // virtual self-loop edges
            atomicAdd(&h[d >> PSHIFT], 1);
        }
    }
    __syncthreads();
    for (int i = t; i < NPART; i += 1024)
        if (h[i]) atomicAdd(&ptotal[i * CPAD], h[i]);
}

// Pass 2: scan 391 partition totals (1 block) -> pbase, init gcur.
__global__ __launch_bounds__(512) void k_pbase(const int* __restrict__ ptotal, int* __restrict__ pbase,
                                               int* __restrict__ gcur, int* __restrict__ rowstart) {
    __shared__ int wsum[8];
    int t = threadIdx.x;
    int v = (t < NPART) ? ptotal[t * CPAD] : 0;
    int excl = block_excl_scan(v, wsum, 8);
    if (t < NPART) { pbase[t] = excl; gcur[t * CPAD] = excl; }
    if (t == 0) { pbase[NPART] = ET; rowstart[NN] = ET; }
}

// Pass 3: LDS hist + global range-reserve per (block,partition) + scatter
// packed (dloc<<17)|src into partition-ordered pairs buffer.
__global__ __launch_bounds__(1024) void k_part(const int* __restrict__ srcA, const int* __restrict__ dstA,
                                               int* __restrict__ gcur, int* __restrict__ pairs) {
    __shared__ int h[NPART];
    __shared__ int cur[NPART];
    int t = threadIdx.x;
    for (int i = t; i < NPART; i += 1024) h[i] = 0;
    __syncthreads();
    int base = blockIdx.x * CHUNK;
#pragma unroll
    for (int k = 0; k < CHUNK / 1024; k++) {
        int e = base + k * 1024 + t;
        if (e < ET) {
            int d = (e < NE) ? dstA[e] : (e - NE);
            atomicAdd(&h[d >> PSHIFT], 1);
        }
    }
    __syncthreads();
    for (int i = t; i < NPART; i += 1024) {
        int c = h[i];
        cur[i] = c ? atomicAdd(&gcur[i * CPAD], c) : 0;   // reserve contiguous range
    }
    __syncthreads();
#pragma unroll
    for (int k = 0; k < CHUNK / 1024; k++) {
        int e = base + k * 1024 + t;
        if (e < ET) {
            int s, d;
            if (e < NE) { s = srcA[e]; d = dstA[e]; }
            else        { s = e - NE;  d = s; }
            int pos = atomicAdd(&cur[d >> PSHIFT], 1);    // LDS atomic
            pairs[pos] = ((d & (PARTW - 1)) << 17) | s;   // src < 2^17, dloc < 2^8
        }
    }
}

// Pass 4: per-partition counting sort. Emits rowstart + packed edge list.
__global__ __launch_bounds__(1024) void k_sort(const int* __restrict__ pbase, const int* __restrict__ pairs,
                                               int* __restrict__ rowstart, int* __restrict__ epack) {
    __shared__ int hist[PARTW];
    __shared__ int sa[PARTW], sb[PARTW];
    int p = blockIdx.x;
    int t = threadIdx.x;
    int n0 = p << PSHIFT;
    int nn = min(PARTW, NN - n0);
    int base = pbase[p];
    int cnt = pbase[p + 1] - base;
    if (t < PARTW) hist[t] = 0;
    __syncthreads();
    for (int i = t; i < cnt; i += 1024)
        atomicAdd(&hist[pairs[base + i] >> 17], 1);
    __syncthreads();
    if (t < PARTW) sa[t] = hist[t];
    __syncthreads();
    int* pin = sa; int* pout = sb;
    for (int off = 1; off < PARTW; off <<= 1) {
        if (t < PARTW) pout[t] = pin[t] + ((t >= off) ? pin[t - off] : 0);
        __syncthreads();
        int* tmp = pin; pin = pout; pout = tmp;
    }
    int excl = 0;
    if (t < PARTW) {
        excl = pin[t] - hist[t];
        if (t < nn) rowstart[n0 + t] = base + excl;
    }
    __syncthreads();
    if (t < PARTW) hist[t] = excl;   // reuse as cursor
    __syncthreads();
    for (int i = t; i < cnt; i += 1024) {
        int v = pairs[base + i];
        int pos = base + atomicAdd(&hist[v >> 17], 1);  // LDS atomic
        epack[pos] = v;                                 // keep dloc packed for k_ew*
    }
}

// ---------------- Layer 1: x@W1, wave-level K-split ----------------
// 4 waves/block; wave kq handles K-quarter [32kq,32kq+32) for 64 nodes.
// W1 index wave-uniform -> s_load. Partials reduced via contiguous-float4 LDS.
// 400k threads (24 waves/CU) vs old 100k (6/CU): fixes the 16%-occupancy stall.

__global__ __launch_bounds__(256) void k_gemm1(const float* __restrict__ x, const float* __restrict__ W1,
        const float* __restrict__ a1s, const float* __restrict__ a1d,
        _Float16* __restrict__ xw1h, float* __restrict__ as1, float* __restrict__ ad1) {
    __shared__ float4 red4[24][64];   // [ (kq-1)*8 + c4 ][ m ]  -- 24 KB
    int t = threadIdx.x;
    int kq = t >> 6;          // wave id = K quarter
    int m  = t & 63;
    int n  = blockIdx.x * 64 + m;
    bool valid = n < NN;
    float acc[F1];
#pragma unroll
    for (int c = 0; c < F1; c++) acc[c] = 0.f;
    float4 xv[8];
#pragma unroll
    for (int j = 0; j < 8; j++) xv[j] = make_float4(0.f, 0.f, 0.f, 0.f);
    if (valid) {
        const float4* x4 = (const float4*)(x + (size_t)n * FIN + kq * 32);
#pragma unroll
        for (int j = 0; j < 8; j++) xv[j] = x4[j];
    }
#pragma unroll
    for (int j = 0; j < 8; j++) {
        float xk[4] = {xv[j].x, xv[j].y, xv[j].z, xv[j].w};
#pragma unroll
        for (int kk = 0; kk < 4; kk++) {
            int k = kq * 32 + j * 4 + kk;   // wave-uniform
#pragma unroll
            for (int c = 0; c < F1; c++)
                acc[c] = fmaf(xk[kk], W1[k * F1 + c], acc[c]);
        }
    }
    if (kq != 0) {
#pragma unroll
        for (int c4 = 0; c4 < 8; c4++)
            red4[(kq - 1) * 8 + c4][m] = make_float4(acc[c4*4], acc[c4*4+1], acc[c4*4+2], acc[c4*4+3]);
    }
    __syncthreads();
    if (kq == 0 && valid) {
#pragma unroll
        for (int q = 0; q < 3; q++)
#pragma unroll
            for (int c4 = 0; c4 < 8; c4++) {
                float4 v = red4[q * 8 + c4][m];
                acc[c4*4]   += v.x;
                acc[c4*4+1] += v.y;
                acc[c4*4+2] += v.z;
                acc[c4*4+3] += v.w;
            }
        half8* o8 = (half8*)(xw1h + (size_t)n * F1);
#pragma unroll
        for (int c8 = 0; c8 < F1 / 8; c8++) {
            half8 o;
#pragma unroll
            for (int k = 0; k < 8; k++) o[k] = (_Float16)acc[c8 * 8 + k];
            o8[c8] = o;
        }
        float ss[H1], dd[H1];
#pragma unroll
        for (int h = 0; h < H1; h++) {
            ss[h] = 0.f; dd[h] = 0.f;
#pragma unroll
            for (int c = 0; c < C1; c++) {
                ss[h] = fmaf(acc[h*C1+c], a1s[h*C1+c], ss[h]);
                dd[h] = fmaf(acc[h*C1+c], a1d[h*C1+c], dd[h]);
            }
        }
        ((float4*)as1)[n] = make_float4(ss[0], ss[1], ss[2], ss[3]);
        ((float4*)ad1)[n] = make_float4(dd[0], dd[1], dd[2], dd[3]);
    }
}

// ---------------- Layer-1 edge weights: ew[pos][h] = exp(leaky(as1[s,h]+ad1[d,h])) ----------------
// One block per partition (d = n0 + (epack>>17)); fully parallel, streaming.

__global__ __launch_bounds__(1024) void k_ew(const int* __restrict__ pbase, const int* __restrict__ epack,
                                             const float* __restrict__ as1, const float* __restrict__ ad1,
                                             half4_t* __restrict__ ew) {
    int p = blockIdx.x;
    int n0 = p << PSHIFT;
    int base = pbase[p], endp = pbase[p + 1];
    const float4* as4 = (const float4*)as1;
    const float4* ad4 = (const float4*)ad1;
    for (int i = base + threadIdx.x; i < endp; i += 1024) {
        int v = epack[i];
        int s = v & SMASK;
        int d = n0 + (v >> 17);
        float4 as = as4[s];
        float4 ad = ad4[d];
        float e0 = as.x + ad.x, e1 = as.y + ad.y, e2 = as.z + ad.z, e3 = as.w + ad.w;
        e0 = (e0 > 0.f) ? e0 : NSLOPE * e0;
        e1 = (e1 > 0.f) ? e1 : NSLOPE * e1;
        e2 = (e2 > 0.f) ? e2 : NSLOPE * e2;
        e3 = (e3 > 0.f) ? e3 : NSLOPE * e3;
        half4_t o;
        o[0] = (_Float16)__expf(e0);
        o[1] = (_Float16)__expf(e1);
        o[2] = (_Float16)__expf(e2);
        o[3] = (_Float16)__expf(e3);
        ew[i] = o;
    }
}

// ---------------- Layer 1 gather: weighted aggregate + bias + ELU -> h1 (fp16) ----------------
// 64 lanes per node; halves process interleaved edges, unroll x4. Pure load/fma loop.

__global__ __launch_bounds__(256) void k_gather1(const int* __restrict__ rowstart, const int* __restrict__ epack,
        const _Float16* __restrict__ ew, const _Float16* __restrict__ xw1h,
        const float* __restrict__ b1, _Float16* __restrict__ h1h) {
    int n = blockIdx.x * 4 + (threadIdx.x >> 6);
    if (n >= NN) return;
    int l = threadIdx.x & 63;
    int c = l & 31;
    int h = c >> 3;
    int half = l >> 5;
    int beg = rowstart[n], end = rowstart[n + 1];
    float accn = 0.f, accd = 0.f;
    int i = beg + half;
    for (; i + 6 < end; i += 8) {
        int v0 = epack[i], v1 = epack[i + 2], v2 = epack[i + 4], v3 = epack[i + 6];
        float w0 = (float)ew[(size_t)i * 4 + h];
        float w1 = (float)ew[(size_t)(i + 2) * 4 + h];
        float w2 = (float)ew[(size_t)(i + 4) * 4 + h];
        float w3 = (float)ew[(size_t)(i + 6) * 4 + h];
        float x0 = (float)xw1h[(v0 & SMASK) * F1 + c];
        float x1 = (float)xw1h[(v1 & SMASK) * F1 + c];
        float x2 = (float)xw1h[(v2 & SMASK) * F1 + c];
        float x3 = (float)xw1h[(v3 & SMASK) * F1 + c];
        accd += (w0 + w1) + (w2 + w3);
        accn = fmaf(w0, x0, fmaf(w1, x1, fmaf(w2, x2, fmaf(w3, x3, accn))));
    }
    for (; i < end; i += 2) {
        int v0 = epack[i];
        float w0 = (float)ew[(size_t)i * 4 + h];
        float x0 = (float)xw1h[(v0 & SMASK) * F1 + c];
        accd += w0;
        accn = fmaf(w0, x0, accn);
    }
    accn += __shfl_xor(accn, 32);
    accd += __shfl_xor(accd, 32);
    float y = accn / accd + b1[c];
    y = (y > 0.f) ? y : expm1f(y);   // ELU
    if (l < 32) h1h[(size_t)n * F1 + c] = (_Float16)y;
}

// ---------------- Layer 2 node transform: h1@W2 + attention coefficients ----------------

__global__ __launch_bounds__(256) void k_node2(const _Float16* __restrict__ h1h, const float* __restrict__ W2,
        const float* __restrict__ a2s, const float* __restrict__ a2d,
        _Float16* __restrict__ xw2h, float* __restrict__ as2, float* __restrict__ ad2) {
    int n = blockIdx.x * 256 + threadIdx.x;
    if (n >= NN) return;
    float acc[FOUT];
#pragma unroll
    for (int j = 0; j < FOUT; j++) acc[j] = 0.f;
    const half8* h8 = (const half8*)(h1h + (size_t)n * F1);
#pragma unroll
    for (int i8 = 0; i8 < F1 / 8; i8++) {
        half8 hv = h8[i8];
#pragma unroll
        for (int kk = 0; kk < 8; kk++) {
            float hk = (float)hv[kk];
            int i = i8 * 8 + kk;
#pragma unroll
            for (int j = 0; j < FOUT; j++)
                acc[j] = fmaf(hk, W2[i * FOUT + j], acc[j]);   // wave-uniform -> scalar
        }
    }
    float ss = 0.f, dd = 0.f;
#pragma unroll
    for (int j = 0; j < FOUT; j++) {
        ss = fmaf(acc[j], a2s[j], ss);
        dd = fmaf(acc[j], a2d[j], dd);
    }
    half8* o8 = (half8*)(xw2h + (size_t)n * FOUT);
#pragma unroll
    for (int j8 = 0; j8 < FOUT / 8; j8++) {
        half8 o;
#pragma unroll
        for (int k = 0; k < 8; k++) o[k] = (_Float16)acc[j8 * 8 + k];
        o8[j8] = o;
    }
    as2[n] = ss;
    ad2[n] = dd;
}

// ---------------- Layer-2 edge weights: ew2[pos] = exp(leaky(as2[s]+ad2[d])) ----------------

__global__ __launch_bounds__(1024) void k_ew2(const int* __restrict__ pbase, const int* __restrict__ epack,
                                              const float* __restrict__ as2, const float* __restrict__ ad2,
                                              _Float16* __restrict__ ew2) {
    int p = blockIdx.x;
    int n0 = p << PSHIFT;
    int base = pbase[p], endp = pbase[p + 1];
    for (int i = base + threadIdx.x; i < endp; i += 1024) {
        int v = epack[i];
        int s = v & SMASK;
        int d = n0 + (v >> 17);
        float e = as2[s] + ad2[d];
        e = (e > 0.f) ? e : NSLOPE * e;
        ew2[i] = (_Float16)__expf(e);
    }
}

// ---------------- Layer 2 gather: softmax-aggregate + bias + log_softmax ----------------
// 64 lanes per node: quarters process interleaved edges, unroll x4.

__global__ __launch_bounds__(256) void k_gather2(const int* __restrict__ rowstart, const int* __restrict__ epack,
        const _Float16* __restrict__ ew2, const _Float16* __restrict__ xw2h,
        const float* __restrict__ b2, float* __restrict__ out) {
    int n = blockIdx.x * 4 + (threadIdx.x >> 6);
    if (n >= NN) return;
    int l = threadIdx.x & 63;
    int c = l & 15;
    int q = l >> 4;
    int beg = rowstart[n], end = rowstart[n + 1];
    float accn = 0.f, accd = 0.f;
    int i = beg + q;
    for (; i + 12 < end; i += 16) {
        int v0 = epack[i], v1 = epack[i + 4], v2 = epack[i + 8], v3 = epack[i + 12];
        float w0 = (float)ew2[i];
        float w1 = (float)ew2[i + 4];
        float w2 = (float)ew2[i + 8];
        float w3 = (float)ew2[i + 12];
        float x0 = (float)xw2h[(v0 & SMASK) * FOUT + c];
        float x1 = (float)xw2h[(v1 & SMASK) * FOUT + c];
        float x2 = (float)xw2h[(v2 & SMASK) * FOUT + c];
        float x3 = (float)xw2h[(v3 & SMASK) * FOUT + c];
        accd += (w0 + w1) + (w2 + w3);
        accn = fmaf(w0, x0, fmaf(w1, x1, fmaf(w2, x2, fmaf(w3, x3, accn))));
    }
    for (; i < end; i += 4) {
        int v0 = epack[i];
        float w0 = (float)ew2[i];
        float x0 = (float)xw2h[(v0 & SMASK) * FOUT + c];
        accd += w0;
        accn = fmaf(w0, x0, accn);
    }
    accn += __shfl_xor(accn, 16);
    accn += __shfl_xor(accn, 32);
    accd += __shfl_xor(accd, 16);
    accd += __shfl_xor(accd, 32);
    float y = accn / accd + b2[c];
    float m = y;
#pragma unroll
    for (int off = 8; off > 0; off >>= 1) m = fmaxf(m, __shfl_xor(m, off));
    float ex = __expf(y - m);
    float sum = ex;
#pragma unroll
    for (int off = 8; off > 0; off >>= 1) sum += __shfl_xor(sum, off);
    if (l < 16) out[(size_t)n * FOUT + c] = y - m - logf(sum);
}

// ---------------- launch ----------------

extern "C" void kernel_launch(void* const* d_in, const int* in_sizes, int n_in,
                              void* d_out, int out_size, void* d_ws, size_t ws_size,
                              hipStream_t stream) {
    const float* x   = (const float*)d_in[0];
    const int*   ei  = (const int*)d_in[1];
    const float* W1  = (const float*)d_in[2];
    const float* a1s = (const float*)d_in[3];
    const float* a1d = (const float*)d_in[4];
    const float* b1  = (const float*)d_in[5];
    const float* W2  = (const float*)d_in[6];
    const float* a2s = (const float*)d_in[7];
    const float* a2d = (const float*)d_in[8];
    const float* b2  = (const float*)d_in[9];
    float* out = (float*)d_out;

    const int* srcA = ei;        // edge_index[0]
    const int* dstA = ei + NE;   // edge_index[1]

    char* w = (char*)d_ws;
    size_t off = 0;
    auto carve = [&](size_t bytes) -> void* {
        void* p = w + off;
        off = (off + bytes + 255) & ~(size_t)255;
        return p;
    };
    _Float16* xw1h = (_Float16*)carve((size_t)NN * F1 * 2);   // 6.4 MB
    float* as1     = (float*)carve((size_t)NN * H1 * 4);      // 1.6 MB
    float* ad1     = (float*)carve((size_t)NN * H1 * 4);      // 1.6 MB
    // pairs (6.8MB) aliases h1h+xw2h (9.6MB): pairs dies at k_sort, h1h/xw2h
    // are written only by later kernels (stream-ordered) -> safe.
    size_t h1_off  = off;
    _Float16* h1h  = (_Float16*)carve((size_t)NN * F1 * 2);   // 6.4 MB
    _Float16* xw2h = (_Float16*)carve((size_t)NN * FOUT * 2); // 3.2 MB
    float* as2     = (float*)carve((size_t)NN * 4);
    float* ad2     = (float*)carve((size_t)NN * 4);
    int* pairs     = (int*)(w + h1_off);                      // alias
    int* rowstart  = (int*)carve((size_t)(NN + 1) * 4);
    int* epack     = (int*)carve((size_t)ET * 4);             // 6.8 MB
    half4_t* ew    = (half4_t*)carve((size_t)ET * 8);         // 13.6 MB
    _Float16* ew2  = (_Float16*)carve((size_t)ET * 2);        // 3.4 MB
    int* ptotal    = (int*)carve((size_t)NPART * CPAD * 4);   // 25 KB
    int* gcur      = (int*)carve((size_t)NPART * CPAD * 4);   // 25 KB
    int* pbase     = (int*)carve((size_t)(NPART + 1) * 4);
    (void)ws_size; (void)in_sizes; (void)n_in; (void)out_size;

    hipMemsetAsync(ptotal, 0, (size_t)NPART * CPAD * 4, stream);

    k_hist  <<<NBLK, 1024, 0, stream>>>(dstA, ptotal);
    k_pbase <<<1, 512, 0, stream>>>(ptotal, pbase, gcur, rowstart);
    k_part  <<<NBLK, 1024, 0, stream>>>(srcA, dstA, gcur, pairs);
    k_sort  <<<NPART, 1024, 0, stream>>>(pbase, pairs, rowstart, epack);

    k_gemm1 <<<(NN + 63) / 64, 256, 0, stream>>>(x, W1, a1s, a1d, xw1h, as1, ad1);
    k_ew    <<<NPART, 1024, 0, stream>>>(pbase, epack, as1, ad1, ew);
    k_gather1<<<(NN + 3) / 4, 256, 0, stream>>>(rowstart, epack, (const _Float16*)ew, xw1h, b1, h1h);
    k_node2 <<<(NN + 255) / 256, 256, 0, stream>>>(h1h, W2, a2s, a2d, xw2h, as2, ad2);
    k_ew2   <<<NPART, 1024, 0, stream>>>(pbase, epack, as2, ad2, ew2);
    k_gather2<<<(NN + 3) / 4, 256, 0, stream>>>(rowstart, epack, ew2, xw2h, b2, out);
}

// Round 9
// 315.632 us; speedup vs baseline: 1.0187x; 1.0187x over previous
//
#include <hip/hip_runtime.h>
#include <math.h>

// Problem constants (from setup_inputs)
#define NN 100000            // nodes
#define NE 1600000           // real edges
#define ET (NE + NN)         // edges + self loops = 1,700,000
#define FIN 128
#define H1 4
#define C1 8
#define F1 32                // H1*C1
#define FOUT 16
#define NSLOPE 0.2f

// Radix-partition parameters (CSR build)
#define PARTW 256                          // nodes per dst-partition
#define PSHIFT 8
#define NPART ((NN + PARTW - 1) / PARTW)   // 391
#define CHUNK 8192                         // edges per hist/part block
#define NBLK ((ET + CHUNK - 1) / CHUNK)    // 208
#define CPAD 16                            // ints: 1 global counter per 64B line
#define SMASK 0x1FFFF                      // low 17 bits = src id

typedef _Float16 half8 __attribute__((ext_vector_type(8)));

// ---------------- scan helpers ----------------

__device__ inline int wave_incl_scan(int v) {
#pragma unroll
    for (int off = 1; off < 64; off <<= 1) {
        int u = __shfl_up(v, off);
        if ((threadIdx.x & 63) >= off) v += u;
    }
    return v;
}

__device__ inline int block_excl_scan(int v, int* wsum, int nw) {
    int t = threadIdx.x, wid = t >> 6, lane = t & 63;
    int incl = wave_incl_scan(v);
    if (lane == 63) wsum[wid] = incl;
    __syncthreads();
    if (wid == 0) {
        int wv = (lane < nw) ? wsum[lane] : 0;
        wv = wave_incl_scan(wv);
        if (lane < nw) wsum[lane] = wv;
    }
    __syncthreads();
    return incl - v + (wid ? wsum[wid - 1] : 0);
}

// ---------------- CSR build ----------------

// Pass 1: LDS histogram -> one global atomicAdd per (block,partition).
__global__ __launch_bounds__(1024) void k_hist(const int* __restrict__ dstA, int* __restrict__ ptotal) {
    __shared__ int h[NPART];
    int t = threadIdx.x;
    for (int i = t; i < NPART; i += 1024) h[i] = 0;
    __syncthreads();
    int base = blockIdx.x * CHUNK;
#pragma unroll
    for (int k = 0; k < CHUNK / 1024; k++) {
        int e = base + k * 1024 + t;
        if (e < ET) {
            int d = (e < NE) ? dstA[e] : (e - NE);   // virtual self-loop edges
            atomicAdd(&h[d >> PSHIFT], 1);
        }
    }
    __syncthreads();
    for (int i = t; i < NPART; i += 1024)
        if (h[i]) atomicAdd(&ptotal[i * CPAD], h[i]);
}

// Pass 2: scan 391 partition totals (1 block) -> pbase, init gcur.
__global__ __launch_bounds__(512) void k_pbase(const int* __restrict__ ptotal, int* __restrict__ pbase,
                                               int* __restrict__ gcur, int* __restrict__ rowstart) {
    __shared__ int wsum[8];
    int t = threadIdx.x;
    int v = (t < NPART) ? ptotal[t * CPAD] : 0;
    int excl = block_excl_scan(v, wsum, 8);
    if (t < NPART) { pbase[t] = excl; gcur[t * CPAD] = excl; }
    if (t == 0) { pbase[NPART] = ET; rowstart[NN] = ET; }
}

// Pass 3: LDS hist + global range-reserve per (block,partition) + scatter
// packed (dloc<<17)|src into partition-ordered pairs buffer.
__global__ __launch_bounds__(1024) void k_part(const int* __restrict__ srcA, const int* __restrict__ dstA,
                                               int* __restrict__ gcur, int* __restrict__ pairs) {
    __shared__ int h[NPART];
    __shared__ int cur[NPART];
    int t = threadIdx.x;
    for (int i = t; i < NPART; i += 1024) h[i] = 0;
    __syncthreads();
    int base = blockIdx.x * CHUNK;
#pragma unroll
    for (int k = 0; k < CHUNK / 1024; k++) {
        int e = base + k * 1024 + t;
        if (e < ET) {
            int d = (e < NE) ? dstA[e] : (e - NE);
            atomicAdd(&h[d >> PSHIFT], 1);
        }
    }
    __syncthreads();
    for (int i = t; i < NPART; i += 1024) {
        int c = h[i];
        cur[i] = c ? atomicAdd(&gcur[i * CPAD], c) : 0;   // reserve contiguous range
    }
    __syncthreads();
#pragma unroll
    for (int k = 0; k < CHUNK / 1024; k++) {
        int e = base + k * 1024 + t;
        if (e < ET) {
            int s, d;
            if (e < NE) { s = srcA[e]; d = dstA[e]; }
            else        { s = e - NE;  d = s; }
            int pos = atomicAdd(&cur[d >> PSHIFT], 1);    // LDS atomic
            pairs[pos] = ((d & (PARTW - 1)) << 17) | s;   // src < 2^17, dloc < 2^8
        }
    }
}

// Pass 4: per-partition counting sort. Emits rowstart + packed edge list.
__global__ __launch_bounds__(1024) void k_sort(const int* __restrict__ pbase, const int* __restrict__ pairs,
                                               int* __restrict__ rowstart, int* __restrict__ epack) {
    __shared__ int hist[PARTW];
    __shared__ int sa[PARTW], sb[PARTW];
    int p = blockIdx.x;
    int t = threadIdx.x;
    int n0 = p << PSHIFT;
    int nn = min(PARTW, NN - n0);
    int base = pbase[p];
    int cnt = pbase[p + 1] - base;
    if (t < PARTW) hist[t] = 0;
    __syncthreads();
    for (int i = t; i < cnt; i += 1024)
        atomicAdd(&hist[pairs[base + i] >> 17], 1);
    __syncthreads();
    if (t < PARTW) sa[t] = hist[t];
    __syncthreads();
    int* pin = sa; int* pout = sb;
    for (int off = 1; off < PARTW; off <<= 1) {
        if (t < PARTW) pout[t] = pin[t] + ((t >= off) ? pin[t - off] : 0);
        __syncthreads();
        int* tmp = pin; pin = pout; pout = tmp;
    }
    int excl = 0;
    if (t < PARTW) {
        excl = pin[t] - hist[t];
        if (t < nn) rowstart[n0 + t] = base + excl;
    }
    __syncthreads();
    if (t < PARTW) hist[t] = excl;   // reuse as cursor
    __syncthreads();
    for (int i = t; i < cnt; i += 1024) {
        int v = pairs[base + i];
        int pos = base + atomicAdd(&hist[v >> 17], 1);  // LDS atomic
        epack[pos] = v;
    }
}

// ---------------- Layer 1: x@W1, LDS-staged coalesced ----------------
// 512 threads / 256 nodes per block. x staged through LDS in 4 K-chunks with
// COALESCED global loads (128B-contiguous per row). Wave-level column split:
// waves 0-3 compute cols 0-15 (heads 0,1), waves 4-7 cols 16-31 (heads 2,3)
// -> W1 index wave-uniform (s_load), acc[16], 2x wave count vs 1-thread/node.
// LDS row stride 33 floats: compute reads bank (m+k)%32 -> conflict-free.

__global__ __launch_bounds__(512) void k_gemm1(const float* __restrict__ x, const float* __restrict__ W1,
        const float* __restrict__ a1s, const float* __restrict__ a1d,
        _Float16* __restrict__ xw1h, float* __restrict__ as1, float* __restrict__ ad1) {
    __shared__ float xs[256 * 33];   // 33.8 KB
    int t = threadIdx.x;
    int m  = t & 255;
    int hf = t >> 8;                 // wave-uniform column half
    int n0 = blockIdx.x * 256;
    int n  = n0 + m;
    float acc[16];
#pragma unroll
    for (int c = 0; c < 16; c++) acc[c] = 0.f;
    const float4* x4 = (const float4*)x;
    for (int kc = 0; kc < 4; kc++) {
        // stage 256 rows x 32 floats (coalesced: 8 consecutive float4 per row)
#pragma unroll
        for (int j = 0; j < 4; j++) {
            int idx = t + 512 * j;           // 0..2047
            int row = idx >> 3, c4 = idx & 7;
            float4 g = make_float4(0.f, 0.f, 0.f, 0.f);
            if (n0 + row < NN) g = x4[(size_t)(n0 + row) * 32 + kc * 8 + c4];
            int b = row * 33 + c4 * 4;
            xs[b] = g.x; xs[b + 1] = g.y; xs[b + 2] = g.z; xs[b + 3] = g.w;
        }
        __syncthreads();
#pragma unroll
        for (int k = 0; k < 32; k++) {
            float xk = xs[m * 33 + k];
            int krow = kc * 32 + k;          // wave-uniform
#pragma unroll
            for (int c = 0; c < 16; c++)
                acc[c] = fmaf(xk, W1[krow * F1 + hf * 16 + c], acc[c]);
        }
        __syncthreads();
    }
    if (n < NN) {
        half8* o8 = (half8*)(xw1h + (size_t)n * F1 + hf * 16);
#pragma unroll
        for (int c8 = 0; c8 < 2; c8++) {
            half8 o;
#pragma unroll
            for (int k = 0; k < 8; k++) o[k] = (_Float16)acc[c8 * 8 + k];
            o8[c8] = o;
        }
        // this half's cols cover heads hf*2 and hf*2+1 completely
        float ss0 = 0.f, dd0 = 0.f, ss1 = 0.f, dd1 = 0.f;
#pragma unroll
        for (int c = 0; c < C1; c++) {
            ss0 = fmaf(acc[c], a1s[hf * 16 + c], ss0);
            dd0 = fmaf(acc[c], a1d[hf * 16 + c], dd0);
            ss1 = fmaf(acc[C1 + c], a1s[hf * 16 + C1 + c], ss1);
            dd1 = fmaf(acc[C1 + c], a1d[hf * 16 + C1 + c], dd1);
        }
        ((float2*)as1)[(size_t)n * 2 + hf] = make_float2(ss0, ss1);
        ((float2*)ad1)[(size_t)n * 2 + hf] = make_float2(dd0, dd1);
    }
}

// ---------------- Layer 1 gather: softmax-aggregate + bias + ELU -> h1 (fp16) ----------------
// 64 lanes per node; halves process interleaved edges, unroll x4. exp in-loop
// (issues once per wave -> lane redundancy is free; beats the ew-detour's
// 27MB round trip, measured R6 vs R8).

__global__ __launch_bounds__(256) void k_gather1(const int* __restrict__ rowstart, const int* __restrict__ epack,
        const float* __restrict__ as1, const float* __restrict__ ad1,
        const _Float16* __restrict__ xw1h, const float* __restrict__ b1,
        _Float16* __restrict__ h1h) {
    int n = blockIdx.x * 4 + (threadIdx.x >> 6);
    if (n >= NN) return;
    int l = threadIdx.x & 63;
    int c = l & 31;
    int h = c >> 3;
    int half = l >> 5;
    float adh = ad1[n * H1 + h];
    int beg = rowstart[n], end = rowstart[n + 1];
    float accn = 0.f, accd = 0.f;
    int i = beg + half;
    for (; i + 6 < end; i += 8) {
        int s0 = epack[i] & SMASK, s1 = epack[i + 2] & SMASK;
        int s2 = epack[i + 4] & SMASK, s3 = epack[i + 6] & SMASK;
        float e0 = as1[s0 * H1 + h] + adh;
        float e1 = as1[s1 * H1 + h] + adh;
        float e2 = as1[s2 * H1 + h] + adh;
        float e3 = as1[s3 * H1 + h] + adh;
        float x0 = (float)xw1h[s0 * F1 + c];
        float x1 = (float)xw1h[s1 * F1 + c];
        float x2 = (float)xw1h[s2 * F1 + c];
        float x3 = (float)xw1h[s3 * F1 + c];
        e0 = (e0 > 0.f) ? e0 : NSLOPE * e0;
        e1 = (e1 > 0.f) ? e1 : NSLOPE * e1;
        e2 = (e2 > 0.f) ? e2 : NSLOPE * e2;
        e3 = (e3 > 0.f) ? e3 : NSLOPE * e3;
        float ee0 = __expf(e0), ee1 = __expf(e1), ee2 = __expf(e2), ee3 = __expf(e3);
        accd += (ee0 + ee1) + (ee2 + ee3);
        accn = fmaf(ee0, x0, fmaf(ee1, x1, fmaf(ee2, x2, fmaf(ee3, x3, accn))));
    }
    for (; i < end; i += 2) {
        int s0 = epack[i] & SMASK;
        float e0 = as1[s0 * H1 + h] + adh;
        float x0 = (float)xw1h[s0 * F1 + c];
        e0 = (e0 > 0.f) ? e0 : NSLOPE * e0;
        float ee0 = __expf(e0);
        accd += ee0;
        accn = fmaf(ee0, x0, accn);
    }
    accn += __shfl_xor(accn, 32);
    accd += __shfl_xor(accd, 32);
    float y = accn / accd + b1[c];
    y = (y > 0.f) ? y : expm1f(y);   // ELU
    if (l < 32) h1h[(size_t)n * F1 + c] = (_Float16)y;
}

// ---------------- Layer 2 node transform: h1@W2 + attention coefficients ----------------

__global__ __launch_bounds__(256) void k_node2(const _Float16* __restrict__ h1h, const float* __restrict__ W2,
        const float* __restrict__ a2s, const float* __restrict__ a2d,
        _Float16* __restrict__ xw2h, float* __restrict__ as2, float* __restrict__ ad2) {
    int n = blockIdx.x * 256 + threadIdx.x;
    if (n >= NN) return;
    float acc[FOUT];
#pragma unroll
    for (int j = 0; j < FOUT; j++) acc[j] = 0.f;
    const half8* h8 = (const half8*)(h1h + (size_t)n * F1);
#pragma unroll
    for (int i8 = 0; i8 < F1 / 8; i8++) {
        half8 hv = h8[i8];
#pragma unroll
        for (int kk = 0; kk < 8; kk++) {
            float hk = (float)hv[kk];
            int i = i8 * 8 + kk;
#pragma unroll
            for (int j = 0; j < FOUT; j++)
                acc[j] = fmaf(hk, W2[i * FOUT + j], acc[j]);   // wave-uniform -> scalar
        }
    }
    float ss = 0.f, dd = 0.f;
#pragma unroll
    for (int j = 0; j < FOUT; j++) {
        ss = fmaf(acc[j], a2s[j], ss);
        dd = fmaf(acc[j], a2d[j], dd);
    }
    half8* o8 = (half8*)(xw2h + (size_t)n * FOUT);
#pragma unroll
    for (int j8 = 0; j8 < FOUT / 8; j8++) {
        half8 o;
#pragma unroll
        for (int k = 0; k < 8; k++) o[k] = (_Float16)acc[j8 * 8 + k];
        o8[j8] = o;
    }
    as2[n] = ss;
    ad2[n] = dd;
}

// ---------------- Layer 2 gather: softmax-aggregate + bias + log_softmax ----------------
// 64 lanes per node: quarters process interleaved edges, unroll x4; exp in-loop.

__global__ __launch_bounds__(256) void k_gather2(const int* __restrict__ rowstart, const int* __restrict__ epack,
        const float* __restrict__ as2, const float* __restrict__ ad2,
        const _Float16* __restrict__ xw2h, const float* __restrict__ b2,
        float* __restrict__ out) {
    int n = blockIdx.x * 4 + (threadIdx.x >> 6);
    if (n >= NN) return;
    int l = threadIdx.x & 63;
    int c = l & 15;
    int q = l >> 4;
    float adn = ad2[n];
    int beg = rowstart[n], end = rowstart[n + 1];
    float accn = 0.f, accd = 0.f;
    int i = beg + q;
    for (; i + 12 < end; i += 16) {
        int s0 = epack[i] & SMASK, s1 = epack[i + 4] & SMASK;
        int s2 = epack[i + 8] & SMASK, s3 = epack[i + 12] & SMASK;
        float e0 = as2[s0] + adn;
        float e1 = as2[s1] + adn;
        float e2 = as2[s2] + adn;
        float e3 = as2[s3] + adn;
        float x0 = (float)xw2h[s0 * FOUT + c];
        float x1 = (float)xw2h[s1 * FOUT + c];
        float x2 = (float)xw2h[s2 * FOUT + c];
        float x3 = (float)xw2h[s3 * FOUT + c];
        e0 = (e0 > 0.f) ? e0 : NSLOPE * e0;
        e1 = (e1 > 0.f) ? e1 : NSLOPE * e1;
        e2 = (e2 > 0.f) ? e2 : NSLOPE * e2;
        e3 = (e3 > 0.f) ? e3 : NSLOPE * e3;
        float ee0 = __expf(e0), ee1 = __expf(e1), ee2 = __expf(e2), ee3 = __expf(e3);
        accd += (ee0 + ee1) + (ee2 + ee3);
        accn = fmaf(ee0, x0, fmaf(ee1, x1, fmaf(ee2, x2, fmaf(ee3, x3, accn))));
    }
    for (; i < end; i += 4) {
        int s0 = epack[i] & SMASK;
        float e0 = as2[s0] + adn;
        float x0 = (float)xw2h[s0 * FOUT + c];
        e0 = (e0 > 0.f) ? e0 : NSLOPE * e0;
        float ee0 = __expf(e0);
        accd += ee0;
        accn = fmaf(ee0, x0, accn);
    }
    accn += __shfl_xor(accn, 16);
    accn += __shfl_xor(accn, 32);
    accd += __shfl_xor(accd, 16);
    accd += __shfl_xor(accd, 32);
    float y = accn / accd + b2[c];
    float m = y;
#pragma unroll
    for (int off = 8; off > 0; off >>= 1) m = fmaxf(m, __shfl_xor(m, off));
    float ex = __expf(y - m);
    float sum = ex;
#pragma unroll
    for (int off = 8; off > 0; off >>= 1) sum += __shfl_xor(sum, off);
    if (l < 16) out[(size_t)n * FOUT + c] = y - m - logf(sum);
}

// ---------------- launch ----------------

extern "C" void kernel_launch(void* const* d_in, const int* in_sizes, int n_in,
                              void* d_out, int out_size, void* d_ws, size_t ws_size,
                              hipStream_t stream) {
    const float* x   = (const float*)d_in[0];
    const int*   ei  = (const int*)d_in[1];
    const float* W1  = (const float*)d_in[2];
    const float* a1s = (const float*)d_in[3];
    const float* a1d = (const float*)d_in[4];
    const float* b1  = (const float*)d_in[5];
    const float* W2  = (const float*)d_in[6];
    const float* a2s = (const float*)d_in[7];
    const float* a2d = (const float*)d_in[8];
    const float* b2  = (const float*)d_in[9];
    float* out = (float*)d_out;

    const int* srcA = ei;        // edge_index[0]
    const int* dstA = ei + NE;   // edge_index[1]

    char* w = (char*)d_ws;
    size_t off = 0;
    auto carve = [&](size_t bytes) -> void* {
        void* p = w + off;
        off = (off + bytes + 255) & ~(size_t)255;
        return p;
    };
    _Float16* xw1h = (_Float16*)carve((size_t)NN * F1 * 2);   // 6.4 MB
    float* as1     = (float*)carve((size_t)NN * H1 * 4);      // 1.6 MB
    float* ad1     = (float*)carve((size_t)NN * H1 * 4);      // 1.6 MB
    // pairs (6.8MB) aliases h1h+xw2h (9.6MB): pairs dies at k_sort, h1h/xw2h
    // are written only by later kernels (stream-ordered) -> safe.
    size_t h1_off  = off;
    _Float16* h1h  = (_Float16*)carve((size_t)NN * F1 * 2);   // 6.4 MB
    _Float16* xw2h = (_Float16*)carve((size_t)NN * FOUT * 2); // 3.2 MB
    float* as2     = (float*)carve((size_t)NN * 4);
    float* ad2     = (float*)carve((size_t)NN * 4);
    int* pairs     = (int*)(w + h1_off);                      // alias
    int* rowstart  = (int*)carve((size_t)(NN + 1) * 4);
    int* epack     = (int*)carve((size_t)ET * 4);             // 6.8 MB
    int* ptotal    = (int*)carve((size_t)NPART * CPAD * 4);   // 25 KB
    int* gcur      = (int*)carve((size_t)NPART * CPAD * 4);   // 25 KB
    int* pbase     = (int*)carve((size_t)(NPART + 1) * 4);
    (void)ws_size; (void)in_sizes; (void)n_in; (void)out_size;

    hipMemsetAsync(ptotal, 0, (size_t)NPART * CPAD * 4, stream);

    k_hist  <<<NBLK, 1024, 0, stream>>>(dstA, ptotal);
    k_pbase <<<1, 512, 0, stream>>>(ptotal, pbase, gcur, rowstart);
    k_part  <<<NBLK, 1024, 0, stream>>>(srcA, dstA, gcur, pairs);
    k_sort  <<<NPART, 1024, 0, stream>>>(pbase, pairs, rowstart, epack);

    k_gemm1 <<<(NN + 255) / 256, 512, 0, stream>>>(x, W1, a1s, a1d, xw1h, as1, ad1);
    k_gather1<<<(NN + 3) / 4, 256, 0, stream>>>(rowstart, epack, as1, ad1, xw1h, b1, h1h);
    k_node2 <<<(NN + 255) / 256, 256, 0, stream>>>(h1h, W2, a2s, a2d, xw2h, as2, ad2);
    k_gather2<<<(NN + 3) / 4, 256, 0, stream>>>(rowstart, epack, as2, ad2, xw2h, b2, out);
}

// Round 10
// 257.570 us; speedup vs baseline: 1.2483x; 1.2254x over previous
//
#include <hip/hip_runtime.h>
#include <math.h>

// Problem constants (from setup_inputs)
#define NN 100000            // nodes
#define NE 1600000           // real edges
#define ET (NE + NN)         // edges + self loops = 1,700,000
#define FIN 128
#define H1 4
#define C1 8
#define F1 32                // H1*C1
#define FOUT 16
#define NSLOPE 0.2f

// Radix-partition parameters (CSR build)
#define PARTW 256                          // nodes per dst-partition
#define PSHIFT 8
#define NPART ((NN + PARTW - 1) / PARTW)   // 391
#define CHUNK 8192                         // edges per hist/part block
#define NBLK ((ET + CHUNK - 1) / CHUNK)    // 208
#define CPAD 16                            // ints: 1 global counter per 64B line
#define SMASK 0x1FFFF                      // low 17 bits = src id

typedef _Float16 half8 __attribute__((ext_vector_type(8)));
typedef float f32x4 __attribute__((ext_vector_type(4)));

// ---------------- scan helpers ----------------

__device__ inline int wave_incl_scan(int v) {
#pragma unroll
    for (int off = 1; off < 64; off <<= 1) {
        int u = __shfl_up(v, off);
        if ((threadIdx.x & 63) >= off) v += u;
    }
    return v;
}

__device__ inline int block_excl_scan(int v, int* wsum, int nw) {
    int t = threadIdx.x, wid = t >> 6, lane = t & 63;
    int incl = wave_incl_scan(v);
    if (lane == 63) wsum[wid] = incl;
    __syncthreads();
    if (wid == 0) {
        int wv = (lane < nw) ? wsum[lane] : 0;
        wv = wave_incl_scan(wv);
        if (lane < nw) wsum[lane] = wv;
    }
    __syncthreads();
    return incl - v + (wid ? wsum[wid - 1] : 0);
}

// ---------------- CSR build ----------------

// Pass 1: LDS histogram -> one global atomicAdd per (block,partition).
__global__ __launch_bounds__(1024) void k_hist(const int* __restrict__ dstA, int* __restrict__ ptotal) {
    __shared__ int h[NPART];
    int t = threadIdx.x;
    for (int i = t; i < NPART; i += 1024) h[i] = 0;
    __syncthreads();
    int base = blockIdx.x * CHUNK;
#pragma unroll
    for (int k = 0; k < CHUNK / 1024; k++) {
        int e = base + k * 1024 + t;
        if (e < ET) {
            int d = (e < NE) ? dstA[e] : (e - NE);   // virtual self-loop edges
            atomicAdd(&h[d >> PSHIFT], 1);
        }
    }
    __syncthreads();
    for (int i = t; i < NPART; i += 1024)
        if (h[i]) atomicAdd(&ptotal[i * CPAD], h[i]);
}

// Pass 2: scan 391 partition totals (1 block) -> pbase, init gcur.
__global__ __launch_bounds__(512) void k_pbase(const int* __restrict__ ptotal, int* __restrict__ pbase,
                                               int* __restrict__ gcur, int* __restrict__ rowstart) {
    __shared__ int wsum[8];
    int t = threadIdx.x;
    int v = (t < NPART) ? ptotal[t * CPAD] : 0;
    int excl = block_excl_scan(v, wsum, 8);
    if (t < NPART) { pbase[t] = excl; gcur[t * CPAD] = excl; }
    if (t == 0) { pbase[NPART] = ET; rowstart[NN] = ET; }
}

// Pass 3: LDS hist + global range-reserve per (block,partition) + scatter
// packed (dloc<<17)|src into partition-ordered pairs buffer.
__global__ __launch_bounds__(1024) void k_part(const int* __restrict__ srcA, const int* __restrict__ dstA,
                                               int* __restrict__ gcur, int* __restrict__ pairs) {
    __shared__ int h[NPART];
    __shared__ int cur[NPART];
    int t = threadIdx.x;
    for (int i = t; i < NPART; i += 1024) h[i] = 0;
    __syncthreads();
    int base = blockIdx.x * CHUNK;
#pragma unroll
    for (int k = 0; k < CHUNK / 1024; k++) {
        int e = base + k * 1024 + t;
        if (e < ET) {
            int d = (e < NE) ? dstA[e] : (e - NE);
            atomicAdd(&h[d >> PSHIFT], 1);
        }
    }
    __syncthreads();
    for (int i = t; i < NPART; i += 1024) {
        int c = h[i];
        cur[i] = c ? atomicAdd(&gcur[i * CPAD], c) : 0;   // reserve contiguous range
    }
    __syncthreads();
#pragma unroll
    for (int k = 0; k < CHUNK / 1024; k++) {
        int e = base + k * 1024 + t;
        if (e < ET) {
            int s, d;
            if (e < NE) { s = srcA[e]; d = dstA[e]; }
            else        { s = e - NE;  d = s; }
            int pos = atomicAdd(&cur[d >> PSHIFT], 1);    // LDS atomic
            pairs[pos] = ((d & (PARTW - 1)) << 17) | s;   // src < 2^17, dloc < 2^8
        }
    }
}

// Pass 4: per-partition counting sort. Emits rowstart + packed edge list.
__global__ __launch_bounds__(1024) void k_sort(const int* __restrict__ pbase, const int* __restrict__ pairs,
                                               int* __restrict__ rowstart, int* __restrict__ epack) {
    __shared__ int hist[PARTW];
    __shared__ int sa[PARTW], sb[PARTW];
    int p = blockIdx.x;
    int t = threadIdx.x;
    int n0 = p << PSHIFT;
    int nn = min(PARTW, NN - n0);
    int base = pbase[p];
    int cnt = pbase[p + 1] - base;
    if (t < PARTW) hist[t] = 0;
    __syncthreads();
    for (int i = t; i < cnt; i += 1024)
        atomicAdd(&hist[pairs[base + i] >> 17], 1);
    __syncthreads();
    if (t < PARTW) sa[t] = hist[t];
    __syncthreads();
    int* pin = sa; int* pout = sb;
    for (int off = 1; off < PARTW; off <<= 1) {
        if (t < PARTW) pout[t] = pin[t] + ((t >= off) ? pin[t - off] : 0);
        __syncthreads();
        int* tmp = pin; pin = pout; pout = tmp;
    }
    int excl = 0;
    if (t < PARTW) {
        excl = pin[t] - hist[t];
        if (t < nn) rowstart[n0 + t] = base + excl;
    }
    __syncthreads();
    if (t < PARTW) hist[t] = excl;   // reuse as cursor
    __syncthreads();
    for (int i = t; i < cnt; i += 1024) {
        int v = pairs[base + i];
        int pos = base + atomicAdd(&hist[v >> 17], 1);  // LDS atomic
        epack[pos] = v;
    }
}

// ---------------- Layer 1: x@W1 via MFMA (fp16 in, fp32 acc) ----------------
// 4 waves/block, 64 nodes/wave (4 M-tiles of 16), 256 nodes/block.
// B = W1 (fp16) staged TRANSPOSED in LDS [n][k] -> B-frag = 1 ds_read_b128
// (m97-verified B^T pattern: lane n=l&15, k=(l>>4)*8+j). A-frag from global
// fp32 row + pack (A[m=l&15][k=(l>>4)*8+j], m120-verified). D (row=(l>>4)*4+r,
// col=l&15, m89-verified) round-trips per-wave LDS -> whole rows per lane for
// the as1/ad1 dots + coalesced half8 stores. M-rows independent -> OOB rows
// clamped and discarded.

__global__ __launch_bounds__(256) void k_gemm1(const float* __restrict__ x, const float* __restrict__ W1,
        const float* __restrict__ a1s, const float* __restrict__ a1d,
        _Float16* __restrict__ xw1h, float* __restrict__ as1, float* __restrict__ ad1) {
    __shared__ _Float16 w1t[F1 * FIN];   // [n][k], 8 KB
    __shared__ float xs[256 * F1];       // [node_loc][col], 32 KB
    int t = threadIdx.x;
    // stage W1 transposed as fp16 (one-time, block-cooperative)
    {
        int i0 = t * 16;
#pragma unroll
        for (int i = 0; i < 16; i++) {
            int idx = i0 + i;
            int k = idx >> 5, n = idx & 31;
            w1t[n * FIN + k] = (_Float16)W1[idx];
        }
    }
    __syncthreads();
    int w = t >> 6, l = t & 63;
    int q = l >> 4, r16 = l & 15;
    int nblk = blockIdx.x * 256;
    int n0 = nblk + w * 64;
    // B fragments: 8 ds_read_b128, live in VGPRs for the whole kernel
    half8 bf[4][2];
#pragma unroll
    for (int kc = 0; kc < 4; kc++)
#pragma unroll
        for (int nt = 0; nt < 2; nt++)
            bf[kc][nt] = *(const half8*)&w1t[(nt * 16 + r16) * FIN + kc * 32 + q * 8];
    // M tiles
#pragma unroll
    for (int mt = 0; mt < 4; mt++) {
        int row = n0 + mt * 16 + r16;
        int rowc = min(row, NN - 1);            // clamp: values discarded for OOB rows
        const float4* xp = (const float4*)(x + (size_t)rowc * FIN + q * 8);
        half8 af[4];
#pragma unroll
        for (int kc = 0; kc < 4; kc++) {
            float4 u = xp[kc * 8];
            float4 v = xp[kc * 8 + 1];
            half8 a;
            a[0] = (_Float16)u.x; a[1] = (_Float16)u.y; a[2] = (_Float16)u.z; a[3] = (_Float16)u.w;
            a[4] = (_Float16)v.x; a[5] = (_Float16)v.y; a[6] = (_Float16)v.z; a[7] = (_Float16)v.w;
            af[kc] = a;
        }
        f32x4 acc0 = {0.f, 0.f, 0.f, 0.f};
        f32x4 acc1 = {0.f, 0.f, 0.f, 0.f};
#pragma unroll
        for (int kc = 0; kc < 4; kc++) {
            acc0 = __builtin_amdgcn_mfma_f32_16x16x32_f16(af[kc], bf[kc][0], acc0, 0, 0, 0);
            acc1 = __builtin_amdgcn_mfma_f32_16x16x32_f16(af[kc], bf[kc][1], acc1, 0, 0, 0);
        }
        // D -> per-wave LDS region (no barrier: wave-local, lgkmcnt ordered)
#pragma unroll
        for (int r = 0; r < 4; r++) {
            xs[(w * 64 + mt * 16 + q * 4 + r) * F1 + r16] = acc0[r];
            xs[(w * 64 + mt * 16 + q * 4 + r) * F1 + 16 + r16] = acc1[r];
        }
    }
    // epilogue: lane l owns node w*64+l (written above by this same wave)
    int node = nblk + w * 64 + l;
    if (node < NN) {
        const float4* xr = (const float4*)&xs[(w * 64 + l) * F1];
        float rowv[F1];
#pragma unroll
        for (int j = 0; j < 8; j++) {
            float4 v = xr[j];
            rowv[j * 4] = v.x; rowv[j * 4 + 1] = v.y; rowv[j * 4 + 2] = v.z; rowv[j * 4 + 3] = v.w;
        }
        half8* o8 = (half8*)(xw1h + (size_t)node * F1);
#pragma unroll
        for (int c8 = 0; c8 < F1 / 8; c8++) {
            half8 o;
#pragma unroll
            for (int k = 0; k < 8; k++) o[k] = (_Float16)rowv[c8 * 8 + k];
            o8[c8] = o;
        }
        float ss[H1], dd[H1];
#pragma unroll
        for (int h = 0; h < H1; h++) {
            ss[h] = 0.f; dd[h] = 0.f;
#pragma unroll
            for (int c = 0; c < C1; c++) {
                ss[h] = fmaf(rowv[h * C1 + c], a1s[h * C1 + c], ss[h]);
                dd[h] = fmaf(rowv[h * C1 + c], a1d[h * C1 + c], dd[h]);
            }
        }
        ((float4*)as1)[node] = make_float4(ss[0], ss[1], ss[2], ss[3]);
        ((float4*)ad1)[node] = make_float4(dd[0], dd[1], dd[2], dd[3]);
    }
}

// ---------------- Layer 1 gather: softmax-aggregate + bias + ELU -> h1 (fp16) ----------------
// 64 lanes per node; halves process interleaved edges, unroll x4; exp in-loop.

__global__ __launch_bounds__(256) void k_gather1(const int* __restrict__ rowstart, const int* __restrict__ epack,
        const float* __restrict__ as1, const float* __restrict__ ad1,
        const _Float16* __restrict__ xw1h, const float* __restrict__ b1,
        _Float16* __restrict__ h1h) {
    int n = blockIdx.x * 4 + (threadIdx.x >> 6);
    if (n >= NN) return;
    int l = threadIdx.x & 63;
    int c = l & 31;
    int h = c >> 3;
    int half = l >> 5;
    float adh = ad1[n * H1 + h];
    int beg = rowstart[n], end = rowstart[n + 1];
    float accn = 0.f, accd = 0.f;
    int i = beg + half;
    for (; i + 6 < end; i += 8) {
        int s0 = epack[i] & SMASK, s1 = epack[i + 2] & SMASK;
        int s2 = epack[i + 4] & SMASK, s3 = epack[i + 6] & SMASK;
        float e0 = as1[s0 * H1 + h] + adh;
        float e1 = as1[s1 * H1 + h] + adh;
        float e2 = as1[s2 * H1 + h] + adh;
        float e3 = as1[s3 * H1 + h] + adh;
        float x0 = (float)xw1h[s0 * F1 + c];
        float x1 = (float)xw1h[s1 * F1 + c];
        float x2 = (float)xw1h[s2 * F1 + c];
        float x3 = (float)xw1h[s3 * F1 + c];
        e0 = (e0 > 0.f) ? e0 : NSLOPE * e0;
        e1 = (e1 > 0.f) ? e1 : NSLOPE * e1;
        e2 = (e2 > 0.f) ? e2 : NSLOPE * e2;
        e3 = (e3 > 0.f) ? e3 : NSLOPE * e3;
        float ee0 = __expf(e0), ee1 = __expf(e1), ee2 = __expf(e2), ee3 = __expf(e3);
        accd += (ee0 + ee1) + (ee2 + ee3);
        accn = fmaf(ee0, x0, fmaf(ee1, x1, fmaf(ee2, x2, fmaf(ee3, x3, accn))));
    }
    for (; i < end; i += 2) {
        int s0 = epack[i] & SMASK;
        float e0 = as1[s0 * H1 + h] + adh;
        float x0 = (float)xw1h[s0 * F1 + c];
        e0 = (e0 > 0.f) ? e0 : NSLOPE * e0;
        float ee0 = __expf(e0);
        accd += ee0;
        accn = fmaf(ee0, x0, accn);
    }
    accn += __shfl_xor(accn, 32);
    accd += __shfl_xor(accd, 32);
    float y = accn / accd + b1[c];
    y = (y > 0.f) ? y : expm1f(y);   // ELU
    if (l < 32) h1h[(size_t)n * F1 + c] = (_Float16)y;
}

// ---------------- Layer 2 node transform: h1@W2 + attention coefficients ----------------

__global__ __launch_bounds__(256) void k_node2(const _Float16* __restrict__ h1h, const float* __restrict__ W2,
        const float* __restrict__ a2s, const float* __restrict__ a2d,
        _Float16* __restrict__ xw2h, float* __restrict__ as2, float* __restrict__ ad2) {
    int n = blockIdx.x * 256 + threadIdx.x;
    if (n >= NN) return;
    float acc[FOUT];
#pragma unroll
    for (int j = 0; j < FOUT; j++) acc[j] = 0.f;
    const half8* h8 = (const half8*)(h1h + (size_t)n * F1);
#pragma unroll
    for (int i8 = 0; i8 < F1 / 8; i8++) {
        half8 hv = h8[i8];
#pragma unroll
        for (int kk = 0; kk < 8; kk++) {
            float hk = (float)hv[kk];
            int i = i8 * 8 + kk;
#pragma unroll
            for (int j = 0; j < FOUT; j++)
                acc[j] = fmaf(hk, W2[i * FOUT + j], acc[j]);   // wave-uniform -> scalar
        }
    }
    float ss = 0.f, dd = 0.f;
#pragma unroll
    for (int j = 0; j < FOUT; j++) {
        ss = fmaf(acc[j], a2s[j], ss);
        dd = fmaf(acc[j], a2d[j], dd);
    }
    half8* o8 = (half8*)(xw2h + (size_t)n * FOUT);
#pragma unroll
    for (int j8 = 0; j8 < FOUT / 8; j8++) {
        half8 o;
#pragma unroll
        for (int k = 0; k < 8; k++) o[k] = (_Float16)acc[j8 * 8 + k];
        o8[j8] = o;
    }
    as2[n] = ss;
    ad2[n] = dd;
}

// ---------------- Layer 2 gather: softmax-aggregate + bias + log_softmax ----------------
// 64 lanes per node: quarters process interleaved edges, unroll x4; exp in-loop.

__global__ __launch_bounds__(256) void k_gather2(const int* __restrict__ rowstart, const int* __restrict__ epack,
        const float* __restrict__ as2, const float* __restrict__ ad2,
        const _Float16* __restrict__ xw2h, const float* __restrict__ b2,
        float* __restrict__ out) {
    int n = blockIdx.x * 4 + (threadIdx.x >> 6);
    if (n >= NN) return;
    int l = threadIdx.x & 63;
    int c = l & 15;
    int q = l >> 4;
    float adn = ad2[n];
    int beg = rowstart[n], end = rowstart[n + 1];
    float accn = 0.f, accd = 0.f;
    int i = beg + q;
    for (; i + 12 < end; i += 16) {
        int s0 = epack[i] & SMASK, s1 = epack[i + 4] & SMASK;
        int s2 = epack[i + 8] & SMASK, s3 = epack[i + 12] & SMASK;
        float e0 = as2[s0] + adn;
        float e1 = as2[s1] + adn;
        float e2 = as2[s2] + adn;
        float e3 = as2[s3] + adn;
        float x0 = (float)xw2h[s0 * FOUT + c];
        float x1 = (float)xw2h[s1 * FOUT + c];
        float x2 = (float)xw2h[s2 * FOUT + c];
        float x3 = (float)xw2h[s3 * FOUT + c];
        e0 = (e0 > 0.f) ? e0 : NSLOPE * e0;
        e1 = (e1 > 0.f) ? e1 : NSLOPE * e1;
        e2 = (e2 > 0.f) ? e2 : NSLOPE * e2;
        e3 = (e3 > 0.f) ? e3 : NSLOPE * e3;
        float ee0 = __expf(e0), ee1 = __expf(e1), ee2 = __expf(e2), ee3 = __expf(e3);
        accd += (ee0 + ee1) + (ee2 + ee3);
        accn = fmaf(ee0, x0, fmaf(ee1, x1, fmaf(ee2, x2, fmaf(ee3, x3, accn))));
    }
    for (; i < end; i += 4) {
        int s0 = epack[i] & SMASK;
        float e0 = as2[s0] + adn;
        float x0 = (float)xw2h[s0 * FOUT + c];
        e0 = (e0 > 0.f) ? e0 : NSLOPE * e0;
        float ee0 = __expf(e0);
        accd += ee0;
        accn = fmaf(ee0, x0, accn);
    }
    accn += __shfl_xor(accn, 16);
    accn += __shfl_xor(accn, 32);
    accd += __shfl_xor(accd, 16);
    accd += __shfl_xor(accd, 32);
    float y = accn / accd + b2[c];
    float m = y;
#pragma unroll
    for (int off = 8; off > 0; off >>= 1) m = fmaxf(m, __shfl_xor(m, off));
    float ex = __expf(y - m);
    float sum = ex;
#pragma unroll
    for (int off = 8; off > 0; off >>= 1) sum += __shfl_xor(sum, off);
    if (l < 16) out[(size_t)n * FOUT + c] = y - m - logf(sum);
}

// ---------------- launch ----------------

extern "C" void kernel_launch(void* const* d_in, const int* in_sizes, int n_in,
                              void* d_out, int out_size, void* d_ws, size_t ws_size,
                              hipStream_t stream) {
    const float* x   = (const float*)d_in[0];
    const int*   ei  = (const int*)d_in[1];
    const float* W1  = (const float*)d_in[2];
    const float* a1s = (const float*)d_in[3];
    const float* a1d = (const float*)d_in[4];
    const float* b1  = (const float*)d_in[5];
    const float* W2  = (const float*)d_in[6];
    const float* a2s = (const float*)d_in[7];
    const float* a2d = (const float*)d_in[8];
    const float* b2  = (const float*)d_in[9];
    float* out = (float*)d_out;

    const int* srcA = ei;        // edge_index[0]
    const int* dstA = ei + NE;   // edge_index[1]

    char* w = (char*)d_ws;
    size_t off = 0;
    auto carve = [&](size_t bytes) -> void* {
        void* p = w + off;
        off = (off + bytes + 255) & ~(size_t)255;
        return p;
    };
    _Float16* xw1h = (_Float16*)carve((size_t)NN * F1 * 2);   // 6.4 MB
    float* as1     = (float*)carve((size_t)NN * H1 * 4);      // 1.6 MB
    float* ad1     = (float*)carve((size_t)NN * H1 * 4);      // 1.6 MB
    // pairs (6.8MB) aliases h1h+xw2h (9.6MB): pairs dies at k_sort, h1h/xw2h
    // are written only by later kernels (stream-ordered) -> safe.
    size_t h1_off  = off;
    _Float16* h1h  = (_Float16*)carve((size_t)NN * F1 * 2);   // 6.4 MB
    _Float16* xw2h = (_Float16*)carve((size_t)NN * FOUT * 2); // 3.2 MB
    float* as2     = (float*)carve((size_t)NN * 4);
    float* ad2     = (float*)carve((size_t)NN * 4);
    int* pairs     = (int*)(w + h1_off);                      // alias
    int* rowstart  = (int*)carve((size_t)(NN + 1) * 4);
    int* epack     = (int*)carve((size_t)ET * 4);             // 6.8 MB
    int* ptotal    = (int*)carve((size_t)NPART * CPAD * 4);   // 25 KB
    int* gcur      = (int*)carve((size_t)NPART * CPAD * 4);   // 25 KB
    int* pbase     = (int*)carve((size_t)(NPART + 1) * 4);
    (void)ws_size; (void)in_sizes; (void)n_in; (void)out_size;

    hipMemsetAsync(ptotal, 0, (size_t)NPART * CPAD * 4, stream);

    k_hist  <<<NBLK, 1024, 0, stream>>>(dstA, ptotal);
    k_pbase <<<1, 512, 0, stream>>>(ptotal, pbase, gcur, rowstart);
    k_part  <<<NBLK, 1024, 0, stream>>>(srcA, dstA, gcur, pairs);
    k_sort  <<<NPART, 1024, 0, stream>>>(pbase, pairs, rowstart, epack);

    k_gemm1 <<<(NN + 255) / 256, 256, 0, stream>>>(x, W1, a1s, a1d, xw1h, as1, ad1);
    k_gather1<<<(NN + 3) / 4, 256, 0, stream>>>(rowstart, epack, as1, ad1, xw1h, b1, h1h);
    k_node2 <<<(NN + 255) / 256, 256, 0, stream>>>(h1h, W2, a2s, a2d, xw2h, as2, ad2);
    k_gather2<<<(NN + 3) / 4, 256, 0, stream>>>(rowstart, epack, as2, ad2, xw2h, b2, out);
}